// Round 6
// baseline (817.921 us; speedup 1.0000x reference)
//
#include <hip/hip_runtime.h>
#include <hip/hip_bf16.h>

typedef __attribute__((ext_vector_type(8))) short bf16x8_t;
typedef __attribute__((ext_vector_type(4))) float f32x4_t;

__device__ __forceinline__ unsigned bfr(float x) {
  unsigned u = __builtin_bit_cast(unsigned, x);
  return (u + 0x7fffu + ((u >> 16) & 1u)) >> 16;
}
__device__ __forceinline__ unsigned pk2(float lo, float hi) {
  return bfr(lo) | (bfr(hi) << 16);
}

// ---------------------------------------------------------------------------
// Conv 3x3 stride2 pad1 + bias + relu + per-channel sum/sumsq stats.
// ---------------------------------------------------------------------------
template<int CIN, int H, int OHS, int BPB, bool BNIN>
__global__ __launch_bounds__(256) void convk(
    const float* __restrict__ x, const float* __restrict__ wgt,
    const float* __restrict__ bias,
    const float* __restrict__ instats,
    const float* __restrict__ ing, const float* __restrict__ inb,
    float* __restrict__ y, float* __restrict__ stats)
{
  constexpr int W = H, HO = H / 2, WO = W / 2;
  constexpr int NR = 2 * OHS + 1;
  constexpr int TW = W + 1;
  constexpr int SPB = HO / OHS;
  constexpr int NSTG = BPB * NR * W;

  __shared__ float tile[2][BPB][NR][TW];
  __shared__ float scb[CIN], shb[CIN];
  __shared__ float sred[24], sqd[24];

  const int tid = threadIdx.x;
  const int b0 = (blockIdx.x / SPB) * BPB;
  const int strip = blockIdx.x % SPB;
  const int oh0 = strip * OHS;

  if (BNIN && tid < CIN) {
    const float cnt = 64.f * H * W;
    const float m = instats[tid] / cnt;
    const float v = instats[24 + tid] / cnt - m * m;
    const float s = rsqrtf(v + 1e-5f) * ing[tid];
    scb[tid] = s;
    shb[tid] = inb[tid] - m * s;
  }
  if (tid < 24) { sred[tid] = 0.f; sqd[tid] = 0.f; }
  for (int i = tid; i < 2 * BPB * NR; i += 256) {
    const int bufi = i / (BPB * NR), rem = i % (BPB * NR);
    tile[bufi][rem / NR][rem % NR][0] = 0.f;
  }
  __syncthreads();

  const int ow  = tid % WO;
  const int ohl = (tid / WO) % OHS;
  const int bs  = tid / (WO * OHS);
  const int oh  = oh0 + ohl;

  float acc[24];
  #pragma unroll
  for (int co = 0; co < 24; ++co) acc[co] = bias[co];

  {
    const float sc = BNIN ? scb[0] : 1.f, sh = BNIN ? shb[0] : 0.f;
    for (int idx = tid; idx < NSTG; idx += 256) {
      const int c = idx % W, rr = idx / W;
      const int rl = rr % NR, sb = rr / NR;
      const int ih = oh0 * 2 - 1 + rl;
      float v = 0.f;
      if (ih >= 0)
        v = x[((size_t)((b0 + sb) * CIN + 0) * H + ih) * W + c] * sc + sh;
      tile[0][sb][rl][c + 1] = v;
    }
  }
  __syncthreads();

  for (int ci = 0; ci < CIN; ++ci) {
    if (ci + 1 < CIN) {
      const float sc = BNIN ? scb[ci + 1] : 1.f, sh = BNIN ? shb[ci + 1] : 0.f;
      for (int idx = tid; idx < NSTG; idx += 256) {
        const int c = idx % W, rr = idx / W;
        const int rl = rr % NR, sb = rr / NR;
        const int ih = oh0 * 2 - 1 + rl;
        float v = 0.f;
        if (ih >= 0)
          v = x[((size_t)((b0 + sb) * CIN + ci + 1) * H + ih) * W + c] * sc + sh;
        tile[(ci + 1) & 1][sb][rl][c + 1] = v;
      }
    }
    float tp[9];
    #pragma unroll
    for (int r = 0; r < 3; ++r)
      #pragma unroll
      for (int s = 0; s < 3; ++s)
        tp[r * 3 + s] = tile[ci & 1][bs][2 * ohl + r][2 * ow + s];
    #pragma unroll
    for (int co = 0; co < 24; ++co) {
      const float* wp = wgt + (size_t)(co * CIN + ci) * 9;
      float a = acc[co];
      #pragma unroll
      for (int k = 0; k < 9; ++k) a += tp[k] * wp[k];
      acc[co] = a;
    }
    __syncthreads();
  }

  const int lane = tid & 63;
  #pragma unroll
  for (int co = 0; co < 24; ++co) {
    const float v = fmaxf(acc[co], 0.f);
    acc[co] = v;
    y[((size_t)((b0 + bs) * 24 + co) * HO + oh) * WO + ow] = v;
  }
  #pragma unroll
  for (int co = 0; co < 24; ++co) {
    float v = acc[co], q = v * v;
    #pragma unroll
    for (int d = 1; d < 64; d <<= 1) {
      v += __shfl_xor(v, d, 64);
      q += __shfl_xor(q, d, 64);
    }
    if (lane == 0) {
      atomicAdd(&sred[co], v);
      atomicAdd(&sqd[co], q);
    }
  }
  __syncthreads();
  if (tid < 24) {
    atomicAdd(&stats[tid], sred[tid]);
    atomicAdd(&stats[24 + tid], sqd[tid]);
  }
}

// ---------------------------------------------------------------------------
// Build A = o @ Wi, B = o @ Wj (BN of x4 fused), plus Cq (blocks with p==0).
// ---------------------------------------------------------------------------
__global__ __launch_bounds__(256) void build_ab(
    const float* __restrict__ x4, const float* __restrict__ stats4,
    const float* __restrict__ g4, const float* __restrict__ b4,
    const float* __restrict__ gw1, const float* __restrict__ gb1,
    const float* __restrict__ qst,
    float* __restrict__ A, float* __restrict__ Bm, float* __restrict__ Cq)
{
  const int bp = blockIdx.x;
  const int b = bp >> 6, p = bp & 63;
  const int t = threadIdx.x;
  __shared__ float o[26];
  if (t < 24) {
    const float m = stats4[t] * (1.f / 4096.f);
    const float v = stats4[24 + t] * (1.f / 4096.f) - m * m;
    const float sc = rsqrtf(v + 1e-5f) * g4[t];
    const float sh = b4[t] - m * sc;
    o[t] = x4[(size_t)(b * 24 + t) * 64 + p] * sc + sh;
  } else if (t == 24) o[24] = (float)(p >> 3);
  else if (t == 25) o[25] = (float)(p & 7);
  __syncthreads();
  float a = 0.f, bb2 = 0.f;
  #pragma unroll
  for (int c = 0; c < 26; ++c) {
    a   += o[c] * gw1[c * 256 + t];
    bb2 += o[c] * gw1[(26 + c) * 256 + t];
  }
  A[(size_t)bp * 256 + t]  = a;
  Bm[(size_t)bp * 256 + t] = bb2;
  if (p == 0) {
    float cqa = gb1[t];
    #pragma unroll
    for (int c = 0; c < 11; ++c)
      cqa += qst[b * 11 + c] * gw1[(52 + c) * 256 + t];
    Cq[b * 256 + t] = cqa;
  }
}

// ---------------------------------------------------------------------------
// Transpose-convert the 3 W matrices (fp32 [k][n]) -> bf16 [n][k]. Grid 192.
// ---------------------------------------------------------------------------
__global__ __launch_bounds__(256) void wt_convert3(
    const float* __restrict__ W2, const float* __restrict__ W3,
    const float* __restrict__ W4, unsigned short* __restrict__ wt)
{
  const int which = blockIdx.x >> 6;
  const float* W = which == 0 ? W2 : which == 1 ? W3 : W4;
  unsigned short* o = wt + (size_t)which * 65536;
  __shared__ float ts[32][33];
  const int blk = blockIdx.x & 63;
  const int k0 = (blk & 7) * 32, n0 = (blk >> 3) * 32;
  const int t = threadIdx.x;
  const int r = t >> 3, c4 = (t & 7) * 4;
  const float4 v = *(const float4*)(W + (size_t)(k0 + r) * 256 + n0 + c4);
  ts[r][c4 + 0] = v.x; ts[r][c4 + 1] = v.y;
  ts[r][c4 + 2] = v.z; ts[r][c4 + 3] = v.w;
  __syncthreads();
  uint2 ov;
  ov.x = pk2(ts[c4 + 0][r], ts[c4 + 1][r]);
  ov.y = pk2(ts[c4 + 2][r], ts[c4 + 3][r]);
  *(uint2*)(o + (size_t)(n0 + r) * 256 + k0 + c4) = ov;
}

// ---------------------------------------------------------------------------
// Pair MLP via MFMA, occupancy-first: block = one (b,j), 64 rows x 256 cols,
// 4 waves, wave tile 64x64 (acc[4][4] = 64 AGPR). W in registers, af
// ping-pong [2][4] (32 VGPR). h in 32KB XOR-swizzled LDS. Target 3 blocks/CU
// (__launch_bounds__(256,3): <=170 unified regs/wave) -> 3 waves/SIMD, and
// desynchronized independent blocks cover each other's stalls.
// ---------------------------------------------------------------------------
__global__ __launch_bounds__(256, 3) void pair_mfma(
    const float* __restrict__ A, const float* __restrict__ Bm,
    const float* __restrict__ Cq,
    const unsigned short* __restrict__ wtall,
    const float* __restrict__ b2, const float* __restrict__ b3,
    const float* __restrict__ b4,
    float* __restrict__ Gpart)
{
  __shared__ __align__(16) unsigned short hsm[64 * 256];   // 32 KB
  __shared__ float gpart[256];

  const int tid = threadIdx.x;
  int bid = blockIdx.x;
  bid = (bid & 7) * 512 + (bid >> 3);      // XCD swizzle (4096 = 8*512)
  const int b = bid >> 6, j = bid & 63;
  const int lane = tid & 63, cg = tid >> 6;   // wave = col-group (64 cols)
  const int l15 = lane & 15, l4 = lane >> 4;
  char* hbase = (char*)hsm;

  // ---- build h1 = relu(A_i + B_j + Cq) bf16, swizzled. row m = i.
  {
    const int m = tid >> 2, seg = tid & 3;
    const float* Ar = A  + (size_t)(b * 64 + m) * 256 + seg * 64;
    const float* Br = Bm + (size_t)(b * 64 + j) * 256 + seg * 64;
    const float* Cr = Cq + (size_t)b * 256 + seg * 64;
    #pragma unroll
    for (int it = 0; it < 8; ++it) {
      const float4 a0 = *(const float4*)(Ar + it * 8);
      const float4 a1 = *(const float4*)(Ar + it * 8 + 4);
      const float4 b0 = *(const float4*)(Br + it * 8);
      const float4 b1 = *(const float4*)(Br + it * 8 + 4);
      const float4 c0 = *(const float4*)(Cr + it * 8);
      const float4 c1 = *(const float4*)(Cr + it * 8 + 4);
      uint4 pk;
      pk.x = pk2(fmaxf(a0.x + b0.x + c0.x, 0.f), fmaxf(a0.y + b0.y + c0.y, 0.f));
      pk.y = pk2(fmaxf(a0.z + b0.z + c0.z, 0.f), fmaxf(a0.w + b0.w + c0.w, 0.f));
      pk.z = pk2(fmaxf(a1.x + b1.x + c1.x, 0.f), fmaxf(a1.y + b1.y + c1.y, 0.f));
      pk.w = pk2(fmaxf(a1.z + b1.z + c1.z, 0.f), fmaxf(a1.w + b1.w + c1.w, 0.f));
      const int kb = seg * 128 + it * 16;
      *(uint4*)(hbase + (size_t)m * 512 + (kb ^ ((m & 7) << 4))) = pk;
    }
  }
  __syncthreads();

  const float* bs3[3] = {b2, b3, b4};

  for (int layer = 0; layer < 3; ++layer) {
    // per-lane W base: output col n = cg*64 + l15 (+a*16), k offset l4*8
    const unsigned short* wrow =
        wtall + (size_t)layer * 65536 + (size_t)(cg * 64 + l15) * 256 + l4 * 8;

    f32x4_t acc[4][4];
    #pragma unroll
    for (int a = 0; a < 4; ++a) {
      const float4 bv = *(const float4*)(bs3[layer] + cg * 64 + a * 16 + l4 * 4);
      #pragma unroll
      for (int t = 0; t < 4; ++t) {
        acc[a][t][0] = bv.x; acc[a][t][1] = bv.y;
        acc[a][t][2] = bv.z; acc[a][t][3] = bv.w;
      }
    }

    bf16x8_t af[2][4];
    #pragma unroll
    for (int a = 0; a < 4; ++a)
      af[0][a] = *(const bf16x8_t*)(wrow + a * 4096);

    #pragma unroll
    for (int ks = 0; ks < 8; ++ks) {
      if (ks < 7) {
        #pragma unroll
        for (int a = 0; a < 4; ++a)
          af[(ks + 1) & 1][a] = *(const bf16x8_t*)(wrow + (ks + 1) * 32 + a * 4096);
      }
      bf16x8_t bf[4];
      #pragma unroll
      for (int t = 0; t < 4; ++t) {
        const int row = t * 16 + l15;
        const int kb = (ks * 64 + l4 * 16) ^ ((row & 7) << 4);
        bf[t] = *(const bf16x8_t*)(hbase + (size_t)row * 512 + kb);
      }
      __builtin_amdgcn_s_setprio(1);
      #pragma unroll
      for (int a = 0; a < 4; ++a)
        #pragma unroll
        for (int t = 0; t < 4; ++t)
          acc[a][t] = __builtin_amdgcn_mfma_f32_16x16x32_bf16(
              af[ks & 1][a], bf[t], acc[a][t], 0, 0, 0);
      __builtin_amdgcn_s_setprio(0);
    }

    if (layer < 2) {
      __syncthreads();   // all h reads of this layer complete
      #pragma unroll
      for (int a = 0; a < 4; ++a) {
        #pragma unroll
        for (int t = 0; t < 4; ++t) {
          const int row = t * 16 + l15;
          const int n0 = cg * 64 + a * 16 + l4 * 4;
          uint2 v;
          v.x = pk2(fmaxf(acc[a][t][0], 0.f), fmaxf(acc[a][t][1], 0.f));
          v.y = pk2(fmaxf(acc[a][t][2], 0.f), fmaxf(acc[a][t][3], 0.f));
          *(uint2*)(hbase + (size_t)row * 512 + ((n0 * 2) ^ ((row & 7) << 4))) = v;
        }
      }
      __syncthreads();   // writes visible before next layer reads
    } else {
      #pragma unroll
      for (int a = 0; a < 4; ++a) {
        f32x4_t s;
        s[0] = s[1] = s[2] = s[3] = 0.f;
        #pragma unroll
        for (int t = 0; t < 4; ++t) {
          s[0] += fmaxf(acc[a][t][0], 0.f);
          s[1] += fmaxf(acc[a][t][1], 0.f);
          s[2] += fmaxf(acc[a][t][2], 0.f);
          s[3] += fmaxf(acc[a][t][3], 0.f);
        }
        #pragma unroll
        for (int d = 1; d < 16; d <<= 1) {
          s[0] += __shfl_xor(s[0], d, 64);
          s[1] += __shfl_xor(s[1], d, 64);
          s[2] += __shfl_xor(s[2], d, 64);
          s[3] += __shfl_xor(s[3], d, 64);
        }
        if (l15 == 0)
          *(f32x4_t*)(&gpart[cg * 64 + a * 16 + l4 * 4]) = s;
      }
      __syncthreads();
      Gpart[(size_t)bid * 256 + tid] = gpart[tid];
    }
  }
}

__global__ __launch_bounds__(256) void reduce_g(
    const float* __restrict__ Gpart, float* __restrict__ g)
{
  const int b = blockIdx.x, t = threadIdx.x;
  float s = 0.f;
  for (int jj = 0; jj < 64; ++jj)
    s += Gpart[(size_t)(b * 64 + jj) * 256 + t];
  g[b * 256 + t] = s;
}

// ---------------------------------------------------------------------------
// f-network + softmax. One block per batch element.
// ---------------------------------------------------------------------------
__global__ __launch_bounds__(256) void fnet(
    const float* __restrict__ g,
    const float* __restrict__ fw1, const float* __restrict__ fb1,
    const float* __restrict__ fw2, const float* __restrict__ fb2,
    const float* __restrict__ fw3, const float* __restrict__ fb3,
    float* __restrict__ out)
{
  const int b = blockIdx.x, t = threadIdx.x;
  __shared__ float s0[256], s1[256], lg[10];
  s0[t] = g[b * 256 + t];
  __syncthreads();
  float acc = fb1[t];
  for (int k = 0; k < 256; ++k) acc += s0[k] * fw1[k * 256 + t];
  s1[t] = fmaxf(acc, 0.f);
  __syncthreads();
  acc = fb2[t];
  for (int k = 0; k < 256; ++k) acc += s1[k] * fw2[k * 256 + t];
  s0[t] = fmaxf(acc, 0.f);
  __syncthreads();
  if (t < 10) {
    float a = fb3[t];
    for (int k = 0; k < 256; ++k) a += s0[k] * fw3[k * 10 + t];
    lg[t] = a;
  }
  __syncthreads();
  if (t == 0) {
    float m = lg[0];
    for (int c = 1; c < 10; ++c) m = fmaxf(m, lg[c]);
    float e[10], sum = 0.f;
    for (int c = 0; c < 10; ++c) { e[c] = expf(lg[c] - m); sum += e[c]; }
    const float inv = 1.f / sum;
    for (int c = 0; c < 10; ++c) out[b * 10 + c] = e[c] * inv;
  }
}

// ---------------------------------------------------------------------------
extern "C" void kernel_launch(void* const* d_in, const int* in_sizes, int n_in,
                              void* d_out, int out_size, void* d_ws, size_t ws_size,
                              hipStream_t stream)
{
  const float* img = (const float*)d_in[0];
  const float* qst = (const float*)d_in[1];
  const float* cw[4] = {(const float*)d_in[2],  (const float*)d_in[6],
                        (const float*)d_in[10], (const float*)d_in[14]};
  const float* cb[4] = {(const float*)d_in[3],  (const float*)d_in[7],
                        (const float*)d_in[11], (const float*)d_in[15]};
  const float* bg[4] = {(const float*)d_in[4],  (const float*)d_in[8],
                        (const float*)d_in[12], (const float*)d_in[16]};
  const float* bb[4] = {(const float*)d_in[5],  (const float*)d_in[9],
                        (const float*)d_in[13], (const float*)d_in[17]};
  const float* gw1 = (const float*)d_in[18];
  const float* gb1 = (const float*)d_in[19];
  const float* gw2 = (const float*)d_in[20];
  const float* gb2 = (const float*)d_in[21];
  const float* gw3 = (const float*)d_in[22];
  const float* gb3 = (const float*)d_in[23];
  const float* gw4 = (const float*)d_in[24];
  const float* gb4 = (const float*)d_in[25];
  const float* fw1 = (const float*)d_in[26];
  const float* fb1 = (const float*)d_in[27];
  const float* fw2 = (const float*)d_in[28];
  const float* fb2 = (const float*)d_in[29];
  const float* fw3 = (const float*)d_in[30];
  const float* fb3 = (const float*)d_in[31];
  float* out = (float*)d_out;

  float* ws    = (float*)d_ws;
  float* x1    = ws;                  // 6291456
  float* x2    = x1 + 6291456;        // 1572864
  float* x3    = x2 + 1572864;        // 393216
  float* x4    = x3 + 393216;         // 98304
  float* Abuf  = x4 + 98304;          // 1048576
  float* Bbuf  = Abuf + 1048576;      // 1048576
  float* Cqb   = Bbuf + 1048576;      // 16384
  float* Gpart = Cqb + 16384;         // 1048576
  float* gbuf  = Gpart + 1048576;     // 16384
  float* stats = gbuf + 16384;        // 192
  unsigned short* wtb = (unsigned short*)(stats + 192);

  hipMemsetAsync(stats, 0, 192 * sizeof(float), stream);

  convk<3, 128, 4, 1, false><<<1024, 256, 0, stream>>>(
      img, cw[0], cb[0], nullptr, nullptr, nullptr, x1, stats + 0);
  convk<24, 64, 8, 1, true><<<256, 256, 0, stream>>>(
      x1, cw[1], cb[1], stats + 0, bg[0], bb[0], x2, stats + 48);
  convk<24, 32, 16, 1, true><<<64, 256, 0, stream>>>(
      x2, cw[2], cb[2], stats + 48, bg[1], bb[1], x3, stats + 96);
  convk<24, 16, 8, 4, true><<<16, 256, 0, stream>>>(
      x3, cw[3], cb[3], stats + 96, bg[2], bb[2], x4, stats + 144);

  build_ab<<<4096, 256, 0, stream>>>(x4, stats + 144, bg[3], bb[3], gw1,
                                     gb1, qst, Abuf, Bbuf, Cqb);
  wt_convert3<<<192, 256, 0, stream>>>(gw2, gw3, gw4, wtb);

  pair_mfma<<<4096, 256, 0, stream>>>(Abuf, Bbuf, Cqb, wtb, gb2, gb3, gb4,
                                      Gpart);
  reduce_g<<<64, 256, 0, stream>>>(Gpart, gbuf);
  fnet<<<64, 256, 0, stream>>>(gbuf, fw1, fb1, fw2, fb2, fw3, fb3, out);
}

// Round 7
// 572.405 us; speedup vs baseline: 1.4289x; 1.4289x over previous
//
#include <hip/hip_runtime.h>
#include <hip/hip_bf16.h>

typedef __attribute__((ext_vector_type(8))) short bf16x8_t;
typedef __attribute__((ext_vector_type(4))) float f32x4_t;

__device__ __forceinline__ unsigned bfr(float x) {
  unsigned u = __builtin_bit_cast(unsigned, x);
  return (u + 0x7fffu + ((u >> 16) & 1u)) >> 16;
}
__device__ __forceinline__ unsigned pk2(float lo, float hi) {
  return bfr(lo) | (bfr(hi) << 16);
}

// ---------------------------------------------------------------------------
// Conv 3x3 stride2 pad1 + bias + relu + per-channel sum/sumsq stats.
// COG=1 (conv1): 256 px/block, every thread does all 24 co (wave-uniform W).
// COG=4 (conv2-4): 64 px/block, wave w computes co [6w,6w+6) for all 64 px
// (readfirstlane keeps weight addressing scalar). Input staged per-ci into
// double-buffered LDS with input-BN applied at stage time (zero-padded).
// ---------------------------------------------------------------------------
template<int CIN, int H, int COG, bool BNIN>
__global__ __launch_bounds__(256) void convk(
    const float* __restrict__ x, const float* __restrict__ wgt,
    const float* __restrict__ bias,
    const float* __restrict__ instats,
    const float* __restrict__ ing, const float* __restrict__ inb,
    float* __restrict__ y, float* __restrict__ stats)
{
  constexpr int W = H, HO = H / 2, WO = W / 2;
  constexpr int PXB = (COG == 1) ? 256 : 64;   // pixels per block
  constexpr int OHS = PXB / WO;                // output rows per block
  constexpr int SPB = HO / OHS;                // strips per image
  constexpr int NR = 2 * OHS + 1;              // staged input rows
  constexpr int TW = W + 1;                    // +1 left zero-pad col
  constexpr int NSTG = NR * W;
  constexpr int NCO = 24 / COG;

  __shared__ float tile[2][NR][TW];
  __shared__ float scb[CIN], shb[CIN];
  __shared__ float sred[24], sqd[24];

  const int tid = threadIdx.x;
  const int b = blockIdx.x / SPB;
  const int strip = blockIdx.x % SPB;
  const int oh0 = strip * OHS;
  const int lane = tid & 63;

  if (BNIN && tid < CIN) {
    const float cnt = 64.f * H * W;
    const float m = instats[tid] / cnt;
    const float v = instats[24 + tid] / cnt - m * m;
    const float s = rsqrtf(v + 1e-5f) * ing[tid];
    scb[tid] = s;
    shb[tid] = inb[tid] - m * s;
  }
  if (tid < 24) { sred[tid] = 0.f; sqd[tid] = 0.f; }
  for (int i = tid; i < 2 * NR; i += 256)
    tile[i / NR][i % NR][0] = 0.f;
  __syncthreads();

  const int px = (COG == 1) ? tid : lane;
  const int ow = px % WO;
  const int ohl = px / WO;
  const int oh = oh0 + ohl;
  const int cb = (COG == 1) ? 0
               : __builtin_amdgcn_readfirstlane(tid >> 6) * NCO;

  float acc[NCO];
  #pragma unroll
  for (int n = 0; n < NCO; ++n) acc[n] = bias[cb + n];

  // stage ci = 0
  {
    const float sc = BNIN ? scb[0] : 1.f, sh = BNIN ? shb[0] : 0.f;
    #pragma unroll
    for (int idx = tid; idx < NSTG; idx += 256) {
      const int c = idx % W, rl = idx / W;
      const int ih = oh0 * 2 - 1 + rl;
      float v = 0.f;
      if (ih >= 0)
        v = x[((size_t)(b * CIN + 0) * H + ih) * W + c] * sc + sh;
      tile[0][rl][c + 1] = v;
    }
  }
  __syncthreads();

  for (int ci = 0; ci < CIN; ++ci) {
    if (ci + 1 < CIN) {
      const float sc = BNIN ? scb[ci + 1] : 1.f, sh = BNIN ? shb[ci + 1] : 0.f;
      #pragma unroll
      for (int idx = tid; idx < NSTG; idx += 256) {
        const int c = idx % W, rl = idx / W;
        const int ih = oh0 * 2 - 1 + rl;
        float v = 0.f;
        if (ih >= 0)
          v = x[((size_t)(b * CIN + ci + 1) * H + ih) * W + c] * sc + sh;
        tile[(ci + 1) & 1][rl][c + 1] = v;
      }
    }
    float tp[9];
    #pragma unroll
    for (int r = 0; r < 3; ++r)
      #pragma unroll
      for (int s = 0; s < 3; ++s)
        tp[r * 3 + s] = tile[ci & 1][2 * ohl + r][2 * ow + s];
    #pragma unroll
    for (int n = 0; n < NCO; ++n) {
      const float* wp = wgt + (size_t)((cb + n) * CIN + ci) * 9;  // scalar
      float a = acc[n];
      #pragma unroll
      for (int k = 0; k < 9; ++k) a += tp[k] * wp[k];
      acc[n] = a;
    }
    __syncthreads();
  }

  // relu + store + stats
  #pragma unroll
  for (int n = 0; n < NCO; ++n) {
    const float v = fmaxf(acc[n], 0.f);
    acc[n] = v;
    y[((size_t)(b * 24 + cb + n) * HO + oh) * WO + ow] = v;
  }
  #pragma unroll
  for (int n = 0; n < NCO; ++n) {
    float v = acc[n], q = v * v;
    #pragma unroll
    for (int d = 1; d < 64; d <<= 1) {
      v += __shfl_xor(v, d, 64);
      q += __shfl_xor(q, d, 64);
    }
    if (lane == 0) {
      atomicAdd(&sred[cb + n], v);
      atomicAdd(&sqd[cb + n], q);
    }
  }
  __syncthreads();
  if (tid < 24) {
    atomicAdd(&stats[tid], sred[tid]);
    atomicAdd(&stats[24 + tid], sqd[tid]);
  }
}

// ---------------------------------------------------------------------------
// Build A = o @ Wi, B = o @ Wj (BN of x4 fused), plus Cq (blocks with p==0).
// ---------------------------------------------------------------------------
__global__ __launch_bounds__(256) void build_ab(
    const float* __restrict__ x4, const float* __restrict__ stats4,
    const float* __restrict__ g4, const float* __restrict__ b4,
    const float* __restrict__ gw1, const float* __restrict__ gb1,
    const float* __restrict__ qst,
    float* __restrict__ A, float* __restrict__ Bm, float* __restrict__ Cq)
{
  const int bp = blockIdx.x;
  const int b = bp >> 6, p = bp & 63;
  const int t = threadIdx.x;
  __shared__ float o[26];
  if (t < 24) {
    const float m = stats4[t] * (1.f / 4096.f);
    const float v = stats4[24 + t] * (1.f / 4096.f) - m * m;
    const float sc = rsqrtf(v + 1e-5f) * g4[t];
    const float sh = b4[t] - m * sc;
    o[t] = x4[(size_t)(b * 24 + t) * 64 + p] * sc + sh;
  } else if (t == 24) o[24] = (float)(p >> 3);
  else if (t == 25) o[25] = (float)(p & 7);
  __syncthreads();
  float a = 0.f, bb2 = 0.f;
  #pragma unroll
  for (int c = 0; c < 26; ++c) {
    a   += o[c] * gw1[c * 256 + t];
    bb2 += o[c] * gw1[(26 + c) * 256 + t];
  }
  A[(size_t)bp * 256 + t]  = a;
  Bm[(size_t)bp * 256 + t] = bb2;
  if (p == 0) {
    float cqa = gb1[t];
    #pragma unroll
    for (int c = 0; c < 11; ++c)
      cqa += qst[b * 11 + c] * gw1[(52 + c) * 256 + t];
    Cq[b * 256 + t] = cqa;
  }
}

// ---------------------------------------------------------------------------
// Transpose-convert the 3 W matrices (fp32 [k][n]) -> bf16 [n][k]. Grid 192.
// ---------------------------------------------------------------------------
__global__ __launch_bounds__(256) void wt_convert3(
    const float* __restrict__ W2, const float* __restrict__ W3,
    const float* __restrict__ W4, unsigned short* __restrict__ wt)
{
  const int which = blockIdx.x >> 6;
  const float* W = which == 0 ? W2 : which == 1 ? W3 : W4;
  unsigned short* o = wt + (size_t)which * 65536;
  __shared__ float ts[32][33];
  const int blk = blockIdx.x & 63;
  const int k0 = (blk & 7) * 32, n0 = (blk >> 3) * 32;
  const int t = threadIdx.x;
  const int r = t >> 3, c4 = (t & 7) * 4;
  const float4 v = *(const float4*)(W + (size_t)(k0 + r) * 256 + n0 + c4);
  ts[r][c4 + 0] = v.x; ts[r][c4 + 1] = v.y;
  ts[r][c4 + 2] = v.z; ts[r][c4 + 3] = v.w;
  __syncthreads();
  uint2 ov;
  ov.x = pk2(ts[c4 + 0][r], ts[c4 + 1][r]);
  ov.y = pk2(ts[c4 + 2][r], ts[c4 + 3][r]);
  *(uint2*)(o + (size_t)(n0 + r) * 256 + k0 + c4) = ov;
}

// ---------------------------------------------------------------------------
// Pair MLP via MFMA (R4 structure — best measured: 253 us). 4 waves / 64 rows
// / 256 cols per block, 2 blocks/CU. W staged in LDS (80B-padded rows,
// double-buffered, prefetch chained across the 3 layers = 24 chunks). h in
// 32KB XOR-swizzled LDS. Per-block partials to Gpart (no global atomics).
// ---------------------------------------------------------------------------
__global__ __launch_bounds__(256) void pair_mfma(
    const float* __restrict__ A, const float* __restrict__ Bm,
    const float* __restrict__ Cq,
    const unsigned short* __restrict__ wtall,
    const float* __restrict__ b2, const float* __restrict__ b3,
    const float* __restrict__ b4,
    float* __restrict__ Gpart)
{
  __shared__ __align__(16) unsigned short hsm[64 * 256];        // 32 KB
  __shared__ __align__(16) unsigned short wbuf[2][256 * 40];    // 40 KB
  __shared__ float gpart[256];

  const int tid = threadIdx.x;
  int bid = blockIdx.x;
  bid = (bid & 7) * 512 + (bid >> 3);      // XCD swizzle (4096 = 8*512)
  const int b = bid >> 6, local = bid & 63;
  const int lane = tid & 63, cg = tid >> 6;
  const int l15 = lane & 15, l4 = lane >> 4;
  char* hbase = (char*)hsm;

  const int r0 = tid >> 2, ss = tid & 3;

  // ---- build h1 = relu(A_i + B_j + Cq) bf16, swizzled
  {
    const int m = tid >> 2, seg = tid & 3;
    const float* Ar = A  + (size_t)(b * 64 + m) * 256 + seg * 64;
    const float* Br = Bm + (size_t)(b * 64 + local) * 256 + seg * 64;
    const float* Cr = Cq + (size_t)b * 256 + seg * 64;
    #pragma unroll
    for (int it = 0; it < 8; ++it) {
      const float4 a0 = *(const float4*)(Ar + it * 8);
      const float4 a1 = *(const float4*)(Ar + it * 8 + 4);
      const float4 b0 = *(const float4*)(Br + it * 8);
      const float4 b1 = *(const float4*)(Br + it * 8 + 4);
      const float4 c0 = *(const float4*)(Cr + it * 8);
      const float4 c1 = *(const float4*)(Cr + it * 8 + 4);
      uint4 pk;
      pk.x = pk2(fmaxf(a0.x + b0.x + c0.x, 0.f), fmaxf(a0.y + b0.y + c0.y, 0.f));
      pk.y = pk2(fmaxf(a0.z + b0.z + c0.z, 0.f), fmaxf(a0.w + b0.w + c0.w, 0.f));
      pk.z = pk2(fmaxf(a1.x + b1.x + c1.x, 0.f), fmaxf(a1.y + b1.y + c1.y, 0.f));
      pk.w = pk2(fmaxf(a1.z + b1.z + c1.z, 0.f), fmaxf(a1.w + b1.w + c1.w, 0.f));
      const int kb = seg * 128 + it * 16;
      *(uint4*)(hbase + (size_t)m * 512 + (kb ^ ((m & 7) << 4))) = pk;
    }
  }

  // ---- stage chunk 0 (layer 0, ks 0)
  {
    #pragma unroll
    for (int q = 0; q < 4; ++q) {
      const int n = r0 + q * 64;
      const uint4 v = *(const uint4*)(wtall + (size_t)n * 256 + ss * 8);
      *(uint4*)(wbuf[0] + n * 40 + ss * 8) = v;
    }
  }
  __syncthreads();

  const float* bs3[3] = {b2, b3, b4};

  for (int layer = 0; layer < 3; ++layer) {
    f32x4_t acc[4][4];
    #pragma unroll
    for (int a = 0; a < 4; ++a) {
      const float4 bv = *(const float4*)(bs3[layer] + cg * 64 + a * 16 + l4 * 4);
      #pragma unroll
      for (int t = 0; t < 4; ++t) {
        acc[a][t][0] = bv.x; acc[a][t][1] = bv.y;
        acc[a][t][2] = bv.z; acc[a][t][3] = bv.w;
      }
    }
    for (int ks = 0; ks < 8; ++ks) {
      const int c = layer * 8 + ks;
      uint4 p0, p1, p2, p3;
      if (c + 1 < 24) {
        const unsigned short* src =
            wtall + (size_t)((c + 1) >> 3) * 65536 + ((c + 1) & 7) * 32;
        p0 = *(const uint4*)(src + (size_t)(r0)       * 256 + ss * 8);
        p1 = *(const uint4*)(src + (size_t)(r0 + 64)  * 256 + ss * 8);
        p2 = *(const uint4*)(src + (size_t)(r0 + 128) * 256 + ss * 8);
        p3 = *(const uint4*)(src + (size_t)(r0 + 192) * 256 + ss * 8);
      }
      bf16x8_t bf[4];
      #pragma unroll
      for (int t = 0; t < 4; ++t) {
        const int row = t * 16 + l15;
        const int kb = ks * 64 + l4 * 16;
        bf[t] = *(const bf16x8_t*)(hbase + (size_t)row * 512 + (kb ^ ((row & 7) << 4)));
      }
      const unsigned short* wrd = wbuf[c & 1];
      #pragma unroll
      for (int a = 0; a < 4; ++a) {
        const bf16x8_t af = *(const bf16x8_t*)(wrd + (cg * 64 + a * 16 + l15) * 40 + l4 * 8);
        #pragma unroll
        for (int t = 0; t < 4; ++t)
          acc[a][t] = __builtin_amdgcn_mfma_f32_16x16x32_bf16(af, bf[t], acc[a][t], 0, 0, 0);
      }
      if (c + 1 < 24) {
        unsigned short* wb = wbuf[(c + 1) & 1];
        *(uint4*)(wb + (r0)       * 40 + ss * 8) = p0;
        *(uint4*)(wb + (r0 + 64)  * 40 + ss * 8) = p1;
        *(uint4*)(wb + (r0 + 128) * 40 + ss * 8) = p2;
        *(uint4*)(wb + (r0 + 192) * 40 + ss * 8) = p3;
      }
      __syncthreads();
    }

    if (layer < 2) {
      #pragma unroll
      for (int a = 0; a < 4; ++a) {
        #pragma unroll
        for (int t = 0; t < 4; ++t) {
          const int row = t * 16 + l15;
          const int n0 = cg * 64 + a * 16 + l4 * 4;
          uint2 v;
          v.x = pk2(fmaxf(acc[a][t][0], 0.f), fmaxf(acc[a][t][1], 0.f));
          v.y = pk2(fmaxf(acc[a][t][2], 0.f), fmaxf(acc[a][t][3], 0.f));
          *(uint2*)(hbase + (size_t)row * 512 + ((n0 * 2) ^ ((row & 7) << 4))) = v;
        }
      }
      __syncthreads();
    } else {
      #pragma unroll
      for (int a = 0; a < 4; ++a) {
        f32x4_t s;
        s[0] = s[1] = s[2] = s[3] = 0.f;
        #pragma unroll
        for (int t = 0; t < 4; ++t) {
          s[0] += fmaxf(acc[a][t][0], 0.f);
          s[1] += fmaxf(acc[a][t][1], 0.f);
          s[2] += fmaxf(acc[a][t][2], 0.f);
          s[3] += fmaxf(acc[a][t][3], 0.f);
        }
        #pragma unroll
        for (int d = 1; d < 16; d <<= 1) {
          s[0] += __shfl_xor(s[0], d, 64);
          s[1] += __shfl_xor(s[1], d, 64);
          s[2] += __shfl_xor(s[2], d, 64);
          s[3] += __shfl_xor(s[3], d, 64);
        }
        if (l15 == 0)
          *(f32x4_t*)(&gpart[cg * 64 + a * 16 + l4 * 4]) = s;
      }
      __syncthreads();
      Gpart[(size_t)(b * 64 + local) * 256 + tid] = gpart[tid];
    }
  }
}

__global__ __launch_bounds__(256) void reduce_g(
    const float* __restrict__ Gpart, float* __restrict__ g)
{
  const int b = blockIdx.x, t = threadIdx.x;
  float s = 0.f;
  for (int j = 0; j < 64; ++j) s += Gpart[(size_t)(b * 64 + j) * 256 + t];
  g[b * 256 + t] = s;
}

// ---------------------------------------------------------------------------
// f-network + softmax. One block per batch element.
// ---------------------------------------------------------------------------
__global__ __launch_bounds__(256) void fnet(
    const float* __restrict__ g,
    const float* __restrict__ fw1, const float* __restrict__ fb1,
    const float* __restrict__ fw2, const float* __restrict__ fb2,
    const float* __restrict__ fw3, const float* __restrict__ fb3,
    float* __restrict__ out)
{
  const int b = blockIdx.x, t = threadIdx.x;
  __shared__ float s0[256], s1[256], lg[10];
  s0[t] = g[b * 256 + t];
  __syncthreads();
  float acc = fb1[t];
  for (int k = 0; k < 256; ++k) acc += s0[k] * fw1[k * 256 + t];
  s1[t] = fmaxf(acc, 0.f);
  __syncthreads();
  acc = fb2[t];
  for (int k = 0; k < 256; ++k) acc += s1[k] * fw2[k * 256 + t];
  s0[t] = fmaxf(acc, 0.f);
  __syncthreads();
  if (t < 10) {
    float a = fb3[t];
    for (int k = 0; k < 256; ++k) a += s0[k] * fw3[k * 10 + t];
    lg[t] = a;
  }
  __syncthreads();
  if (t == 0) {
    float m = lg[0];
    for (int c = 1; c < 10; ++c) m = fmaxf(m, lg[c]);
    float e[10], sum = 0.f;
    for (int c = 0; c < 10; ++c) { e[c] = expf(lg[c] - m); sum += e[c]; }
    const float inv = 1.f / sum;
    for (int c = 0; c < 10; ++c) out[b * 10 + c] = e[c] * inv;
  }
}

// ---------------------------------------------------------------------------
extern "C" void kernel_launch(void* const* d_in, const int* in_sizes, int n_in,
                              void* d_out, int out_size, void* d_ws, size_t ws_size,
                              hipStream_t stream)
{
  const float* img = (const float*)d_in[0];
  const float* qst = (const float*)d_in[1];
  const float* cw[4] = {(const float*)d_in[2],  (const float*)d_in[6],
                        (const float*)d_in[10], (const float*)d_in[14]};
  const float* cb[4] = {(const float*)d_in[3],  (const float*)d_in[7],
                        (const float*)d_in[11], (const float*)d_in[15]};
  const float* bg[4] = {(const float*)d_in[4],  (const float*)d_in[8],
                        (const float*)d_in[12], (const float*)d_in[16]};
  const float* bb[4] = {(const float*)d_in[5],  (const float*)d_in[9],
                        (const float*)d_in[13], (const float*)d_in[17]};
  const float* gw1 = (const float*)d_in[18];
  const float* gb1 = (const float*)d_in[19];
  const float* gw2 = (const float*)d_in[20];
  const float* gb2 = (const float*)d_in[21];
  const float* gw3 = (const float*)d_in[22];
  const float* gb3 = (const float*)d_in[23];
  const float* gw4 = (const float*)d_in[24];
  const float* gb4 = (const float*)d_in[25];
  const float* fw1 = (const float*)d_in[26];
  const float* fb1 = (const float*)d_in[27];
  const float* fw2 = (const float*)d_in[28];
  const float* fb2 = (const float*)d_in[29];
  const float* fw3 = (const float*)d_in[30];
  const float* fb3 = (const float*)d_in[31];
  float* out = (float*)d_out;

  float* ws    = (float*)d_ws;
  float* x1    = ws;                  // 6291456
  float* x2    = x1 + 6291456;        // 1572864
  float* x3    = x2 + 1572864;        // 393216
  float* x4    = x3 + 393216;         // 98304
  float* Abuf  = x4 + 98304;          // 1048576
  float* Bbuf  = Abuf + 1048576;      // 1048576
  float* Cqb   = Bbuf + 1048576;      // 16384
  float* Gpart = Cqb + 16384;         // 1048576
  float* gbuf  = Gpart + 1048576;     // 16384
  float* stats = gbuf + 16384;        // 192
  unsigned short* wtb = (unsigned short*)(stats + 192);

  hipMemsetAsync(stats, 0, 192 * sizeof(float), stream);

  convk<3, 128, 1, false><<<1024, 256, 0, stream>>>(
      img, cw[0], cb[0], nullptr, nullptr, nullptr, x1, stats + 0);
  convk<24, 64, 4, true><<<1024, 256, 0, stream>>>(
      x1, cw[1], cb[1], stats + 0, bg[0], bb[0], x2, stats + 48);
  convk<24, 32, 4, true><<<256, 256, 0, stream>>>(
      x2, cw[2], cb[2], stats + 48, bg[1], bb[1], x3, stats + 96);
  convk<24, 16, 4, true><<<64, 256, 0, stream>>>(
      x3, cw[3], cb[3], stats + 96, bg[2], bb[2], x4, stats + 144);

  build_ab<<<4096, 256, 0, stream>>>(x4, stats + 144, bg[3], bb[3], gw1,
                                     gb1, qst, Abuf, Bbuf, Cqb);
  wt_convert3<<<192, 256, 0, stream>>>(gw2, gw3, gw4, wtb);

  pair_mfma<<<4096, 256, 0, stream>>>(Abuf, Bbuf, Cqb, wtb, gb2, gb3, gb4,
                                      Gpart);
  reduce_g<<<64, 256, 0, stream>>>(Gpart, gbuf);
  fnet<<<64, 256, 0, stream>>>(gbuf, fw1, fb1, fw2, fb2, fw3, fb3, out);
}

// Round 9
// 555.955 us; speedup vs baseline: 1.4712x; 1.0296x over previous
//
#include <hip/hip_runtime.h>
#include <hip/hip_bf16.h>

typedef __attribute__((ext_vector_type(8))) short bf16x8_t;
typedef __attribute__((ext_vector_type(4))) float f32x4_t;

__device__ __forceinline__ unsigned bfr(float x) {
  unsigned u = __builtin_bit_cast(unsigned, x);
  return (u + 0x7fffu + ((u >> 16) & 1u)) >> 16;
}
__device__ __forceinline__ unsigned pk2(float lo, float hi) {
  return bfr(lo) | (bfr(hi) << 16);
}

// ---------------------------------------------------------------------------
// Conv 3x3 stride2 pad1 + bias + relu + per-channel sum/sumsq stats.
// COG=1 (conv1): 256 px/block, every thread does all 24 co (wave-uniform W).
// COG=4 (conv2-4): 64 px/block, wave w computes co [6w,6w+6) for all 64 px.
// Input staged per-ci into double-buffered LDS, input-BN folded at stage time.
// ---------------------------------------------------------------------------
template<int CIN, int H, int COG, bool BNIN>
__global__ __launch_bounds__(256) void convk(
    const float* __restrict__ x, const float* __restrict__ wgt,
    const float* __restrict__ bias,
    const float* __restrict__ instats,
    const float* __restrict__ ing, const float* __restrict__ inb,
    float* __restrict__ y, float* __restrict__ stats)
{
  constexpr int W = H, HO = H / 2, WO = W / 2;
  constexpr int PXB = (COG == 1) ? 256 : 64;
  constexpr int OHS = PXB / WO;
  constexpr int SPB = HO / OHS;
  constexpr int NR = 2 * OHS + 1;
  constexpr int TW = W + 1;
  constexpr int NSTG = NR * W;
  constexpr int NCO = 24 / COG;

  __shared__ float tile[2][NR][TW];
  __shared__ float scb[CIN], shb[CIN];
  __shared__ float sred[24], sqd[24];

  const int tid = threadIdx.x;
  const int b = blockIdx.x / SPB;
  const int strip = blockIdx.x % SPB;
  const int oh0 = strip * OHS;
  const int lane = tid & 63;

  if (BNIN && tid < CIN) {
    const float cnt = 64.f * H * W;
    const float m = instats[tid] / cnt;
    const float v = instats[24 + tid] / cnt - m * m;
    const float s = rsqrtf(v + 1e-5f) * ing[tid];
    scb[tid] = s;
    shb[tid] = inb[tid] - m * s;
  }
  if (tid < 24) { sred[tid] = 0.f; sqd[tid] = 0.f; }
  for (int i = tid; i < 2 * NR; i += 256)
    tile[i / NR][i % NR][0] = 0.f;
  __syncthreads();

  const int px = (COG == 1) ? tid : lane;
  const int ow = px % WO;
  const int ohl = px / WO;
  const int oh = oh0 + ohl;
  const int cb = (COG == 1) ? 0
               : __builtin_amdgcn_readfirstlane(tid >> 6) * NCO;

  float acc[NCO];
  #pragma unroll
  for (int n = 0; n < NCO; ++n) acc[n] = bias[cb + n];

  {
    const float sc = BNIN ? scb[0] : 1.f, sh = BNIN ? shb[0] : 0.f;
    #pragma unroll
    for (int idx = tid; idx < NSTG; idx += 256) {
      const int c = idx % W, rl = idx / W;
      const int ih = oh0 * 2 - 1 + rl;
      float v = 0.f;
      if (ih >= 0)
        v = x[((size_t)(b * CIN + 0) * H + ih) * W + c] * sc + sh;
      tile[0][rl][c + 1] = v;
    }
  }
  __syncthreads();

  for (int ci = 0; ci < CIN; ++ci) {
    if (ci + 1 < CIN) {
      const float sc = BNIN ? scb[ci + 1] : 1.f, sh = BNIN ? shb[ci + 1] : 0.f;
      #pragma unroll
      for (int idx = tid; idx < NSTG; idx += 256) {
        const int c = idx % W, rl = idx / W;
        const int ih = oh0 * 2 - 1 + rl;
        float v = 0.f;
        if (ih >= 0)
          v = x[((size_t)(b * CIN + ci + 1) * H + ih) * W + c] * sc + sh;
        tile[(ci + 1) & 1][rl][c + 1] = v;
      }
    }
    float tp[9];
    #pragma unroll
    for (int r = 0; r < 3; ++r)
      #pragma unroll
      for (int s = 0; s < 3; ++s)
        tp[r * 3 + s] = tile[ci & 1][2 * ohl + r][2 * ow + s];
    #pragma unroll
    for (int n = 0; n < NCO; ++n) {
      const float* wp = wgt + (size_t)((cb + n) * CIN + ci) * 9;  // scalar
      float a = acc[n];
      #pragma unroll
      for (int k = 0; k < 9; ++k) a += tp[k] * wp[k];
      acc[n] = a;
    }
    __syncthreads();
  }

  #pragma unroll
  for (int n = 0; n < NCO; ++n) {
    const float v = fmaxf(acc[n], 0.f);
    acc[n] = v;
    y[((size_t)(b * 24 + cb + n) * HO + oh) * WO + ow] = v;
  }
  #pragma unroll
  for (int n = 0; n < NCO; ++n) {
    float v = acc[n], q = v * v;
    #pragma unroll
    for (int d = 1; d < 64; d <<= 1) {
      v += __shfl_xor(v, d, 64);
      q += __shfl_xor(q, d, 64);
    }
    if (lane == 0) {
      atomicAdd(&sred[cb + n], v);
      atomicAdd(&sqd[cb + n], q);
    }
  }
  __syncthreads();
  if (tid < 24) {
    atomicAdd(&stats[tid], sred[tid]);
    atomicAdd(&stats[24 + tid], sqd[tid]);
  }
}

// ---------------------------------------------------------------------------
// Build A = o @ Wi, B = o @ Wj (BN of x4 fused). Block = (b, 8 pixels):
// gw1 column loads shared across the 8 pixels. Cq from pg==0 blocks.
// ---------------------------------------------------------------------------
__global__ __launch_bounds__(256) void build_ab(
    const float* __restrict__ x4, const float* __restrict__ stats4,
    const float* __restrict__ g4, const float* __restrict__ b4,
    const float* __restrict__ gw1, const float* __restrict__ gb1,
    const float* __restrict__ qst,
    float* __restrict__ A, float* __restrict__ Bm, float* __restrict__ Cq)
{
  const int bp = blockIdx.x;            // 512 = 64 b x 8 pixel-groups
  const int b = bp >> 3, pg = bp & 7;
  const int t = threadIdx.x;
  __shared__ float o[8][26];
  if (t < 208) {
    const int r = t / 26, c = t % 26;
    if (c < 24) {
      const float m = stats4[c] * (1.f / 4096.f);
      const float v = stats4[24 + c] * (1.f / 4096.f) - m * m;
      const float sc = rsqrtf(v + 1e-5f) * g4[c];
      const float sh = b4[c] - m * sc;
      o[r][c] = x4[(size_t)(b * 24 + c) * 64 + pg * 8 + r] * sc + sh;
    } else if (c == 24) o[r][24] = (float)pg;
    else                o[r][25] = (float)r;
  }
  __syncthreads();
  float accA[8], accB[8];
  #pragma unroll
  for (int r = 0; r < 8; ++r) { accA[r] = 0.f; accB[r] = 0.f; }
  #pragma unroll
  for (int c = 0; c < 26; ++c) {
    const float wi = gw1[c * 256 + t];
    const float wj = gw1[(26 + c) * 256 + t];
    #pragma unroll
    for (int r = 0; r < 8; ++r) {
      accA[r] += o[r][c] * wi;
      accB[r] += o[r][c] * wj;
    }
  }
  #pragma unroll
  for (int r = 0; r < 8; ++r) {
    A[(size_t)(b * 64 + pg * 8 + r) * 256 + t]  = accA[r];
    Bm[(size_t)(b * 64 + pg * 8 + r) * 256 + t] = accB[r];
  }
  if (pg == 0) {
    float cqa = gb1[t];
    #pragma unroll
    for (int c = 0; c < 11; ++c)
      cqa += qst[b * 11 + c] * gw1[(52 + c) * 256 + t];
    Cq[b * 256 + t] = cqa;
  }
}

// ---------------------------------------------------------------------------
// Convert W2/W3/W4 (fp32 [k][n]) to FRAGMENT-MAJOR bf16:
// chunk c = layer*8+ks (K=32 slice); within chunk: frag f = (cg*4+a)*64+ln,
// 8 halfs = Wt[n = cg*64+a*16+(ln&15)][k = ks*32+(ln>>4)*8 .. +8].
// Makes pair_mfma's LDS staging a LINEAR copy and af reads lane-linear.
// Chunk = 8192 halfs = 16 KB = 1024 uint4.
// ---------------------------------------------------------------------------
__global__ __launch_bounds__(256) void wt_convert_frag(
    const float* __restrict__ W2, const float* __restrict__ W3,
    const float* __restrict__ W4, unsigned short* __restrict__ wt)
{
  const int c = blockIdx.x;             // 0..23
  const int layer = c >> 3, ks = c & 7;
  const float* W = layer == 0 ? W2 : layer == 1 ? W3 : W4;
  const int t = threadIdx.x;
  #pragma unroll
  for (int q = 0; q < 4; ++q) {
    const int f = q * 256 + t;          // frag id 0..1023
    const int cg = f >> 8, a = (f >> 6) & 3, ln = f & 63;
    const int n = cg * 64 + a * 16 + (ln & 15);
    const int k0 = ks * 32 + (ln >> 4) * 8;
    float w[8];
    #pragma unroll
    for (int u = 0; u < 8; ++u) w[u] = W[(size_t)(k0 + u) * 256 + n];
    uint4 ov;
    ov.x = pk2(w[0], w[1]); ov.y = pk2(w[2], w[3]);
    ov.z = pk2(w[4], w[5]); ov.w = pk2(w[6], w[7]);
    *(uint4*)(wt + (size_t)c * 8192 + (size_t)f * 8) = ov;
  }
}

// ---------------------------------------------------------------------------
// Pair MLP via MFMA (R4 schedule, fragment-major W). 4 waves / 64 rows / 256
// cols per block, 2 blocks/CU. W LDS-dbuf staged as a LINEAR 16KB copy per
// K=32 chunk (conflict-free both sides); af read = base + lane*16B.
// h in 32KB XOR-swizzled LDS.
// ---------------------------------------------------------------------------
__global__ __launch_bounds__(256) void pair_mfma(
    const float* __restrict__ A, const float* __restrict__ Bm,
    const float* __restrict__ Cq,
    const unsigned short* __restrict__ wtall,
    const float* __restrict__ b2, const float* __restrict__ b3,
    const float* __restrict__ b4,
    float* __restrict__ Gpart)
{
  __shared__ __align__(16) unsigned short hsm[64 * 256];     // 32 KB
  __shared__ __align__(16) unsigned short wbuf[2][8192];     // 32 KB
  __shared__ float gpart[256];

  const int tid = threadIdx.x;
  int bid = blockIdx.x;
  bid = (bid & 7) * 512 + (bid >> 3);      // XCD swizzle (4096 = 8*512)
  const int b = bid >> 6, local = bid & 63;
  const int lane = tid & 63, cg = tid >> 6;
  const int l15 = lane & 15, l4 = lane >> 4;
  char* hbase = (char*)hsm;

  // ---- build h1 = relu(A_i + B_j + Cq) bf16, swizzled
  {
    const int m = tid >> 2, seg = tid & 3;
    const float* Ar = A  + (size_t)(b * 64 + m) * 256 + seg * 64;
    const float* Br = Bm + (size_t)(b * 64 + local) * 256 + seg * 64;
    const float* Cr = Cq + (size_t)b * 256 + seg * 64;
    #pragma unroll
    for (int it = 0; it < 8; ++it) {
      const float4 a0 = *(const float4*)(Ar + it * 8);
      const float4 a1 = *(const float4*)(Ar + it * 8 + 4);
      const float4 b0 = *(const float4*)(Br + it * 8);
      const float4 b1 = *(const float4*)(Br + it * 8 + 4);
      const float4 c0 = *(const float4*)(Cr + it * 8);
      const float4 c1 = *(const float4*)(Cr + it * 8 + 4);
      uint4 pk;
      pk.x = pk2(fmaxf(a0.x + b0.x + c0.x, 0.f), fmaxf(a0.y + b0.y + c0.y, 0.f));
      pk.y = pk2(fmaxf(a0.z + b0.z + c0.z, 0.f), fmaxf(a0.w + b0.w + c0.w, 0.f));
      pk.z = pk2(fmaxf(a1.x + b1.x + c1.x, 0.f), fmaxf(a1.y + b1.y + c1.y, 0.f));
      pk.w = pk2(fmaxf(a1.z + b1.z + c1.z, 0.f), fmaxf(a1.w + b1.w + c1.w, 0.f));
      const int kb = seg * 128 + it * 16;
      *(uint4*)(hbase + (size_t)m * 512 + (kb ^ ((m & 7) << 4))) = pk;
    }
  }

  // ---- stage chunk 0 (linear 16KB copy, 4 x uint4 per thread)
  {
    const uint4* src = (const uint4*)wtall;
    uint4* dst = (uint4*)wbuf[0];
    #pragma unroll
    for (int q = 0; q < 4; ++q)
      dst[q * 256 + tid] = src[q * 256 + tid];
  }
  __syncthreads();

  const float* bs3[3] = {b2, b3, b4};

  for (int layer = 0; layer < 3; ++layer) {
    f32x4_t acc[4][4];
    #pragma unroll
    for (int a = 0; a < 4; ++a) {
      const float4 bv = *(const float4*)(bs3[layer] + cg * 64 + a * 16 + l4 * 4);
      #pragma unroll
      for (int t = 0; t < 4; ++t) {
        acc[a][t][0] = bv.x; acc[a][t][1] = bv.y;
        acc[a][t][2] = bv.z; acc[a][t][3] = bv.w;
      }
    }
    for (int ks = 0; ks < 8; ++ks) {
      const int c = layer * 8 + ks;
      uint4 p0, p1, p2, p3;
      if (c + 1 < 24) {
        // chunk stride = 1024 uint4 (16 KB)  [R8 bug was *512]
        const uint4* src = (const uint4*)wtall + (size_t)(c + 1) * 1024;
        p0 = src[0 * 256 + tid];
        p1 = src[1 * 256 + tid];
        p2 = src[2 * 256 + tid];
        p3 = src[3 * 256 + tid];
      }
      bf16x8_t bf[4];
      #pragma unroll
      for (int t = 0; t < 4; ++t) {
        const int row = t * 16 + l15;
        const int kb = ks * 64 + l4 * 16;
        bf[t] = *(const bf16x8_t*)(hbase + (size_t)row * 512 + (kb ^ ((row & 7) << 4)));
      }
      const unsigned short* wrd = wbuf[c & 1];
      #pragma unroll
      for (int a = 0; a < 4; ++a) {
        const bf16x8_t af = *(const bf16x8_t*)(wrd + ((size_t)(cg * 4 + a) * 64 + lane) * 8);
        #pragma unroll
        for (int t = 0; t < 4; ++t)
          acc[a][t] = __builtin_amdgcn_mfma_f32_16x16x32_bf16(af, bf[t], acc[a][t], 0, 0, 0);
      }
      if (c + 1 < 24) {
        uint4* wb = (uint4*)wbuf[(c + 1) & 1];
        wb[0 * 256 + tid] = p0;
        wb[1 * 256 + tid] = p1;
        wb[2 * 256 + tid] = p2;
        wb[3 * 256 + tid] = p3;
      }
      __syncthreads();
    }

    if (layer < 2) {
      #pragma unroll
      for (int a = 0; a < 4; ++a) {
        #pragma unroll
        for (int t = 0; t < 4; ++t) {
          const int row = t * 16 + l15;
          const int n0 = cg * 64 + a * 16 + l4 * 4;
          uint2 v;
          v.x = pk2(fmaxf(acc[a][t][0], 0.f), fmaxf(acc[a][t][1], 0.f));
          v.y = pk2(fmaxf(acc[a][t][2], 0.f), fmaxf(acc[a][t][3], 0.f));
          *(uint2*)(hbase + (size_t)row * 512 + ((n0 * 2) ^ ((row & 7) << 4))) = v;
        }
      }
      __syncthreads();
    } else {
      #pragma unroll
      for (int a = 0; a < 4; ++a) {
        f32x4_t s;
        s[0] = s[1] = s[2] = s[3] = 0.f;
        #pragma unroll
        for (int t = 0; t < 4; ++t) {
          s[0] += fmaxf(acc[a][t][0], 0.f);
          s[1] += fmaxf(acc[a][t][1], 0.f);
          s[2] += fmaxf(acc[a][t][2], 0.f);
          s[3] += fmaxf(acc[a][t][3], 0.f);
        }
        #pragma unroll
        for (int d = 1; d < 16; d <<= 1) {
          s[0] += __shfl_xor(s[0], d, 64);
          s[1] += __shfl_xor(s[1], d, 64);
          s[2] += __shfl_xor(s[2], d, 64);
          s[3] += __shfl_xor(s[3], d, 64);
        }
        if (l15 == 0)
          *(f32x4_t*)(&gpart[cg * 64 + a * 16 + l4 * 4]) = s;
      }
      __syncthreads();
      Gpart[(size_t)(b * 64 + local) * 256 + tid] = gpart[tid];
    }
  }
}

// ---------------------------------------------------------------------------
// g-reduction + f-network + softmax fused. One block per batch element.
// ---------------------------------------------------------------------------
__global__ __launch_bounds__(256) void fnet(
    const float* __restrict__ Gpart,
    const float* __restrict__ fw1, const float* __restrict__ fb1,
    const float* __restrict__ fw2, const float* __restrict__ fb2,
    const float* __restrict__ fw3, const float* __restrict__ fb3,
    float* __restrict__ out)
{
  const int b = blockIdx.x, t = threadIdx.x;
  __shared__ float s0[256], s1[256], lg[10];
  float g = 0.f;
  for (int j = 0; j < 64; ++j)
    g += Gpart[(size_t)(b * 64 + j) * 256 + t];
  s0[t] = g;
  __syncthreads();
  float acc = fb1[t];
  for (int k = 0; k < 256; ++k) acc += s0[k] * fw1[k * 256 + t];
  s1[t] = fmaxf(acc, 0.f);
  __syncthreads();
  acc = fb2[t];
  for (int k = 0; k < 256; ++k) acc += s1[k] * fw2[k * 256 + t];
  s0[t] = fmaxf(acc, 0.f);
  __syncthreads();
  if (t < 10) {
    float a = fb3[t];
    for (int k = 0; k < 256; ++k) a += s0[k] * fw3[k * 10 + t];
    lg[t] = a;
  }
  __syncthreads();
  if (t == 0) {
    float m = lg[0];
    for (int c = 1; c < 10; ++c) m = fmaxf(m, lg[c]);
    float e[10], sum = 0.f;
    for (int c = 0; c < 10; ++c) { e[c] = expf(lg[c] - m); sum += e[c]; }
    const float inv = 1.f / sum;
    for (int c = 0; c < 10; ++c) out[b * 10 + c] = e[c] * inv;
  }
}

// ---------------------------------------------------------------------------
extern "C" void kernel_launch(void* const* d_in, const int* in_sizes, int n_in,
                              void* d_out, int out_size, void* d_ws, size_t ws_size,
                              hipStream_t stream)
{
  const float* img = (const float*)d_in[0];
  const float* qst = (const float*)d_in[1];
  const float* cw[4] = {(const float*)d_in[2],  (const float*)d_in[6],
                        (const float*)d_in[10], (const float*)d_in[14]};
  const float* cb[4] = {(const float*)d_in[3],  (const float*)d_in[7],
                        (const float*)d_in[11], (const float*)d_in[15]};
  const float* bg[4] = {(const float*)d_in[4],  (const float*)d_in[8],
                        (const float*)d_in[12], (const float*)d_in[16]};
  const float* bb[4] = {(const float*)d_in[5],  (const float*)d_in[9],
                        (const float*)d_in[13], (const float*)d_in[17]};
  const float* gw1 = (const float*)d_in[18];
  const float* gb1 = (const float*)d_in[19];
  const float* gw2 = (const float*)d_in[20];
  const float* gb2 = (const float*)d_in[21];
  const float* gw3 = (const float*)d_in[22];
  const float* gb3 = (const float*)d_in[23];
  const float* gw4 = (const float*)d_in[24];
  const float* gb4 = (const float*)d_in[25];
  const float* fw1 = (const float*)d_in[26];
  const float* fb1 = (const float*)d_in[27];
  const float* fw2 = (const float*)d_in[28];
  const float* fb2 = (const float*)d_in[29];
  const float* fw3 = (const float*)d_in[30];
  const float* fb3 = (const float*)d_in[31];
  float* out = (float*)d_out;

  float* ws    = (float*)d_ws;
  float* x1    = ws;                  // 6291456
  float* x2    = x1 + 6291456;        // 1572864
  float* x3    = x2 + 1572864;        // 393216
  float* x4    = x3 + 393216;         // 98304
  float* Abuf  = x4 + 98304;          // 1048576
  float* Bbuf  = Abuf + 1048576;      // 1048576
  float* Cqb   = Bbuf + 1048576;      // 16384
  float* Gpart = Cqb + 16384;         // 1048576
  float* stats = Gpart + 1048576;     // 192
  unsigned short* wtb = (unsigned short*)(stats + 192);  // 196608 halfs

  hipMemsetAsync(stats, 0, 192 * sizeof(float), stream);

  wt_convert_frag<<<24, 256, 0, stream>>>(gw2, gw3, gw4, wtb);

  convk<3, 128, 1, false><<<1024, 256, 0, stream>>>(
      img, cw[0], cb[0], nullptr, nullptr, nullptr, x1, stats + 0);
  convk<24, 64, 4, true><<<1024, 256, 0, stream>>>(
      x1, cw[1], cb[1], stats + 0, bg[0], bb[0], x2, stats + 48);
  convk<24, 32, 4, true><<<256, 256, 0, stream>>>(
      x2, cw[2], cb[2], stats + 48, bg[1], bb[1], x3, stats + 96);
  convk<24, 16, 4, true><<<64, 256, 0, stream>>>(
      x3, cw[3], cb[3], stats + 96, bg[2], bb[2], x4, stats + 144);

  build_ab<<<512, 256, 0, stream>>>(x4, stats + 144, bg[3], bb[3], gw1,
                                    gb1, qst, Abuf, Bbuf, Cqb);

  pair_mfma<<<4096, 256, 0, stream>>>(Abuf, Bbuf, Cqb, wtb, gb2, gb3, gb4,
                                      Gpart);
  fnet<<<64, 256, 0, stream>>>(Gpart, fw1, fb1, fw2, fb2, fw3, fb3, out);
}

// Round 10
// 539.588 us; speedup vs baseline: 1.5158x; 1.0303x over previous
//
#include <hip/hip_runtime.h>
#include <hip/hip_bf16.h>

typedef __attribute__((ext_vector_type(8))) short bf16x8_t;
typedef __attribute__((ext_vector_type(4))) float f32x4_t;

__device__ __forceinline__ unsigned bfr(float x) {
  unsigned u = __builtin_bit_cast(unsigned, x);
  return (u + 0x7fffu + ((u >> 16) & 1u)) >> 16;
}
__device__ __forceinline__ unsigned pk2(float lo, float hi) {
  return bfr(lo) | (bfr(hi) << 16);
}

// ---------------------------------------------------------------------------
// Conv 3x3 stride2 pad1 + bias + relu + per-channel sum/sumsq stats.
// COG=1 (conv1): 256 px/block, every thread does all 24 co (wave-uniform W).
// COG=4 (conv2-4): 64 px/block, wave w computes co [6w,6w+6) for all 64 px.
// Input staged per-ci into double-buffered LDS, input-BN folded at stage time.
// ---------------------------------------------------------------------------
template<int CIN, int H, int COG, bool BNIN>
__global__ __launch_bounds__(256) void convk(
    const float* __restrict__ x, const float* __restrict__ wgt,
    const float* __restrict__ bias,
    const float* __restrict__ instats,
    const float* __restrict__ ing, const float* __restrict__ inb,
    float* __restrict__ y, float* __restrict__ stats)
{
  constexpr int W = H, HO = H / 2, WO = W / 2;
  constexpr int PXB = (COG == 1) ? 256 : 64;
  constexpr int OHS = PXB / WO;
  constexpr int SPB = HO / OHS;
  constexpr int NR = 2 * OHS + 1;
  constexpr int TW = W + 1;
  constexpr int NSTG = NR * W;
  constexpr int NCO = 24 / COG;

  __shared__ float tile[2][NR][TW];
  __shared__ float scb[CIN], shb[CIN];
  __shared__ float sred[24], sqd[24];

  const int tid = threadIdx.x;
  const int b = blockIdx.x / SPB;
  const int strip = blockIdx.x % SPB;
  const int oh0 = strip * OHS;
  const int lane = tid & 63;

  if (BNIN && tid < CIN) {
    const float cnt = 64.f * H * W;
    const float m = instats[tid] / cnt;
    const float v = instats[24 + tid] / cnt - m * m;
    const float s = rsqrtf(v + 1e-5f) * ing[tid];
    scb[tid] = s;
    shb[tid] = inb[tid] - m * s;
  }
  if (tid < 24) { sred[tid] = 0.f; sqd[tid] = 0.f; }
  for (int i = tid; i < 2 * NR; i += 256)
    tile[i / NR][i % NR][0] = 0.f;
  __syncthreads();

  const int px = (COG == 1) ? tid : lane;
  const int ow = px % WO;
  const int ohl = px / WO;
  const int oh = oh0 + ohl;
  const int cb = (COG == 1) ? 0
               : __builtin_amdgcn_readfirstlane(tid >> 6) * NCO;

  float acc[NCO];
  #pragma unroll
  for (int n = 0; n < NCO; ++n) acc[n] = bias[cb + n];

  {
    const float sc = BNIN ? scb[0] : 1.f, sh = BNIN ? shb[0] : 0.f;
    #pragma unroll
    for (int idx = tid; idx < NSTG; idx += 256) {
      const int c = idx % W, rl = idx / W;
      const int ih = oh0 * 2 - 1 + rl;
      float v = 0.f;
      if (ih >= 0)
        v = x[((size_t)(b * CIN + 0) * H + ih) * W + c] * sc + sh;
      tile[0][rl][c + 1] = v;
    }
  }
  __syncthreads();

  for (int ci = 0; ci < CIN; ++ci) {
    if (ci + 1 < CIN) {
      const float sc = BNIN ? scb[ci + 1] : 1.f, sh = BNIN ? shb[ci + 1] : 0.f;
      #pragma unroll
      for (int idx = tid; idx < NSTG; idx += 256) {
        const int c = idx % W, rl = idx / W;
        const int ih = oh0 * 2 - 1 + rl;
        float v = 0.f;
        if (ih >= 0)
          v = x[((size_t)(b * CIN + ci + 1) * H + ih) * W + c] * sc + sh;
        tile[(ci + 1) & 1][rl][c + 1] = v;
      }
    }
    float tp[9];
    #pragma unroll
    for (int r = 0; r < 3; ++r)
      #pragma unroll
      for (int s = 0; s < 3; ++s)
        tp[r * 3 + s] = tile[ci & 1][2 * ohl + r][2 * ow + s];
    #pragma unroll
    for (int n = 0; n < NCO; ++n) {
      const float* wp = wgt + (size_t)((cb + n) * CIN + ci) * 9;  // scalar
      float a = acc[n];
      #pragma unroll
      for (int k = 0; k < 9; ++k) a += tp[k] * wp[k];
      acc[n] = a;
    }
    __syncthreads();
  }

  #pragma unroll
  for (int n = 0; n < NCO; ++n) {
    const float v = fmaxf(acc[n], 0.f);
    acc[n] = v;
    y[((size_t)(b * 24 + cb + n) * HO + oh) * WO + ow] = v;
  }
  #pragma unroll
  for (int n = 0; n < NCO; ++n) {
    float v = acc[n], q = v * v;
    #pragma unroll
    for (int d = 1; d < 64; d <<= 1) {
      v += __shfl_xor(v, d, 64);
      q += __shfl_xor(q, d, 64);
    }
    if (lane == 0) {
      atomicAdd(&sred[cb + n], v);
      atomicAdd(&sqd[cb + n], q);
    }
  }
  __syncthreads();
  if (tid < 24) {
    atomicAdd(&stats[tid], sred[tid]);
    atomicAdd(&stats[24 + tid], sqd[tid]);
  }
}

// ---------------------------------------------------------------------------
// Build A = o @ Wi, B = o @ Wj (BN of x4 fused). Block = (b, 8 pixels):
// gw1 column loads shared across the 8 pixels. Cq from pg==0 blocks.
// ---------------------------------------------------------------------------
__global__ __launch_bounds__(256) void build_ab(
    const float* __restrict__ x4, const float* __restrict__ stats4,
    const float* __restrict__ g4, const float* __restrict__ b4,
    const float* __restrict__ gw1, const float* __restrict__ gb1,
    const float* __restrict__ qst,
    float* __restrict__ A, float* __restrict__ Bm, float* __restrict__ Cq)
{
  const int bp = blockIdx.x;            // 512 = 64 b x 8 pixel-groups
  const int b = bp >> 3, pg = bp & 7;
  const int t = threadIdx.x;
  __shared__ float o[8][26];
  if (t < 208) {
    const int r = t / 26, c = t % 26;
    if (c < 24) {
      const float m = stats4[c] * (1.f / 4096.f);
      const float v = stats4[24 + c] * (1.f / 4096.f) - m * m;
      const float sc = rsqrtf(v + 1e-5f) * g4[c];
      const float sh = b4[c] - m * sc;
      o[r][c] = x4[(size_t)(b * 24 + c) * 64 + pg * 8 + r] * sc + sh;
    } else if (c == 24) o[r][24] = (float)pg;
    else                o[r][25] = (float)r;
  }
  __syncthreads();
  float accA[8], accB[8];
  #pragma unroll
  for (int r = 0; r < 8; ++r) { accA[r] = 0.f; accB[r] = 0.f; }
  #pragma unroll
  for (int c = 0; c < 26; ++c) {
    const float wi = gw1[c * 256 + t];
    const float wj = gw1[(26 + c) * 256 + t];
    #pragma unroll
    for (int r = 0; r < 8; ++r) {
      accA[r] += o[r][c] * wi;
      accB[r] += o[r][c] * wj;
    }
  }
  #pragma unroll
  for (int r = 0; r < 8; ++r) {
    A[(size_t)(b * 64 + pg * 8 + r) * 256 + t]  = accA[r];
    Bm[(size_t)(b * 64 + pg * 8 + r) * 256 + t] = accB[r];
  }
  if (pg == 0) {
    float cqa = gb1[t];
    #pragma unroll
    for (int c = 0; c < 11; ++c)
      cqa += qst[b * 11 + c] * gw1[(52 + c) * 256 + t];
    Cq[b * 256 + t] = cqa;
  }
}

// ---------------------------------------------------------------------------
// Convert W2/W3/W4 (fp32 [k][n]) to FRAGMENT-MAJOR bf16:
// chunk c = layer*8+ks (K=32 slice); frag f = (cg*4+a)*64+ln;
// 8 halfs = Wt[n = cg*64+a*16+(ln&15)][k = ks*32+(ln>>4)*8 .. +8].
// Per-lane af loads in pair_mfma are then contiguous/coalesced.
// Block 0 also zeroes the stats buffer (replaces a memset launch).
// ---------------------------------------------------------------------------
__global__ __launch_bounds__(256) void wt_convert_frag(
    const float* __restrict__ W2, const float* __restrict__ W3,
    const float* __restrict__ W4, unsigned short* __restrict__ wt,
    float* __restrict__ stats)
{
  const int c = blockIdx.x;             // 0..23
  const int t = threadIdx.x;
  if (c == 0 && t < 192) stats[t] = 0.f;
  const int layer = c >> 3, ks = c & 7;
  const float* W = layer == 0 ? W2 : layer == 1 ? W3 : W4;
  #pragma unroll
  for (int q = 0; q < 4; ++q) {
    const int f = q * 256 + t;          // frag id 0..1023
    const int cg = f >> 8, a = (f >> 6) & 3, ln = f & 63;
    const int n = cg * 64 + a * 16 + (ln & 15);
    const int k0 = ks * 32 + (ln >> 4) * 8;
    float w[8];
    #pragma unroll
    for (int u = 0; u < 8; ++u) w[u] = W[(size_t)(k0 + u) * 256 + n];
    uint4 ov;
    ov.x = pk2(w[0], w[1]); ov.y = pk2(w[2], w[3]);
    ov.z = pk2(w[4], w[5]); ov.w = pk2(w[6], w[7]);
    *(uint4*)(wt + (size_t)c * 8192 + (size_t)f * 8) = ov;
  }
}

// ---------------------------------------------------------------------------
// Pair MLP via MFMA — barrier-minimal schedule. 4 waves / 64 rows / 256 cols
// per block, 2 blocks/CU. W lives in REGISTERS: af[8][4] (128 VGPR) loaded
// once per layer via coalesced fragment-major loads — no W LDS, no staging
// barriers. h ping-pong in 2x32KB swizzled LDS: ONE barrier per layer
// transition. Barriers/block: ~4 (was ~29).
// ---------------------------------------------------------------------------
__global__ __launch_bounds__(256, 2) void pair_mfma(
    const float* __restrict__ A, const float* __restrict__ Bm,
    const float* __restrict__ Cq,
    const unsigned short* __restrict__ wtall,
    const float* __restrict__ b2, const float* __restrict__ b3,
    const float* __restrict__ b4,
    float* __restrict__ Gpart)
{
  __shared__ __align__(16) unsigned short hsm[2][64 * 256];   // 2 x 32 KB
  __shared__ float gpart[256];

  const int tid = threadIdx.x;
  int bid = blockIdx.x;
  bid = (bid & 7) * 512 + (bid >> 3);      // XCD swizzle (4096 = 8*512)
  const int b = bid >> 6, local = bid & 63;
  const int lane = tid & 63, cg = tid >> 6;
  const int l15 = lane & 15, l4 = lane >> 4;

  // ---- build h1 = relu(A_i + B_j + Cq) bf16, swizzled, into hsm[0]
  {
    char* h0 = (char*)hsm[0];
    const int m = tid >> 2, seg = tid & 3;
    const float* Ar = A  + (size_t)(b * 64 + m) * 256 + seg * 64;
    const float* Br = Bm + (size_t)(b * 64 + local) * 256 + seg * 64;
    const float* Cr = Cq + (size_t)b * 256 + seg * 64;
    #pragma unroll
    for (int it = 0; it < 8; ++it) {
      const float4 a0 = *(const float4*)(Ar + it * 8);
      const float4 a1 = *(const float4*)(Ar + it * 8 + 4);
      const float4 b0 = *(const float4*)(Br + it * 8);
      const float4 b1 = *(const float4*)(Br + it * 8 + 4);
      const float4 c0 = *(const float4*)(Cr + it * 8);
      const float4 c1 = *(const float4*)(Cr + it * 8 + 4);
      uint4 pk;
      pk.x = pk2(fmaxf(a0.x + b0.x + c0.x, 0.f), fmaxf(a0.y + b0.y + c0.y, 0.f));
      pk.y = pk2(fmaxf(a0.z + b0.z + c0.z, 0.f), fmaxf(a0.w + b0.w + c0.w, 0.f));
      pk.z = pk2(fmaxf(a1.x + b1.x + c1.x, 0.f), fmaxf(a1.y + b1.y + c1.y, 0.f));
      pk.w = pk2(fmaxf(a1.z + b1.z + c1.z, 0.f), fmaxf(a1.w + b1.w + c1.w, 0.f));
      const int kb = seg * 128 + it * 16;
      *(uint4*)(h0 + (size_t)m * 512 + (kb ^ ((m & 7) << 4))) = pk;
    }
  }
  __syncthreads();

  const float* bs3[3] = {b2, b3, b4};

  #pragma unroll
  for (int layer = 0; layer < 3; ++layer) {
    const char* hread = (const char*)hsm[layer & 1];
    char* hwrite = (char*)hsm[(layer & 1) ^ 1];

    // ---- whole-layer W into registers (coalesced per-lane loads, L2-hot)
    bf16x8_t af[8][4];
    {
      const unsigned short* wl =
          wtall + (size_t)layer * 65536 + ((size_t)(cg * 4) * 64 + lane) * 8;
      #pragma unroll
      for (int ks = 0; ks < 8; ++ks)
        #pragma unroll
        for (int a = 0; a < 4; ++a)
          af[ks][a] = *(const bf16x8_t*)(wl + (size_t)ks * 8192 + a * 512);
    }

    f32x4_t acc[4][4];
    #pragma unroll
    for (int a = 0; a < 4; ++a) {
      const float4 bv = *(const float4*)(bs3[layer] + cg * 64 + a * 16 + l4 * 4);
      #pragma unroll
      for (int t = 0; t < 4; ++t) {
        acc[a][t][0] = bv.x; acc[a][t][1] = bv.y;
        acc[a][t][2] = bv.z; acc[a][t][3] = bv.w;
      }
    }

    #pragma unroll
    for (int ks = 0; ks < 8; ++ks) {
      bf16x8_t bf[4];
      #pragma unroll
      for (int t = 0; t < 4; ++t) {
        const int row = t * 16 + l15;
        const int kb = ks * 64 + l4 * 16;
        bf[t] = *(const bf16x8_t*)(hread + (size_t)row * 512 + (kb ^ ((row & 7) << 4)));
      }
      #pragma unroll
      for (int a = 0; a < 4; ++a)
        #pragma unroll
        for (int t = 0; t < 4; ++t)
          acc[a][t] = __builtin_amdgcn_mfma_f32_16x16x32_bf16(
              af[ks][a], bf[t], acc[a][t], 0, 0, 0);
    }

    if (layer < 2) {
      // write relu(h_next) to the OTHER buffer; one barrier makes it visible
      #pragma unroll
      for (int a = 0; a < 4; ++a) {
        #pragma unroll
        for (int t = 0; t < 4; ++t) {
          const int row = t * 16 + l15;
          const int n0 = cg * 64 + a * 16 + l4 * 4;
          uint2 v;
          v.x = pk2(fmaxf(acc[a][t][0], 0.f), fmaxf(acc[a][t][1], 0.f));
          v.y = pk2(fmaxf(acc[a][t][2], 0.f), fmaxf(acc[a][t][3], 0.f));
          *(uint2*)(hwrite + (size_t)row * 512 + ((n0 * 2) ^ ((row & 7) << 4))) = v;
        }
      }
      __syncthreads();
    } else {
      #pragma unroll
      for (int a = 0; a < 4; ++a) {
        f32x4_t s;
        s[0] = s[1] = s[2] = s[3] = 0.f;
        #pragma unroll
        for (int t = 0; t < 4; ++t) {
          s[0] += fmaxf(acc[a][t][0], 0.f);
          s[1] += fmaxf(acc[a][t][1], 0.f);
          s[2] += fmaxf(acc[a][t][2], 0.f);
          s[3] += fmaxf(acc[a][t][3], 0.f);
        }
        #pragma unroll
        for (int d = 1; d < 16; d <<= 1) {
          s[0] += __shfl_xor(s[0], d, 64);
          s[1] += __shfl_xor(s[1], d, 64);
          s[2] += __shfl_xor(s[2], d, 64);
          s[3] += __shfl_xor(s[3], d, 64);
        }
        if (l15 == 0)
          *(f32x4_t*)(&gpart[cg * 64 + a * 16 + l4 * 4]) = s;
      }
      __syncthreads();
      Gpart[(size_t)(b * 64 + local) * 256 + tid] = gpart[tid];
    }
  }
}

// ---------------------------------------------------------------------------
// g-reduction + f-network + softmax fused. One block per batch element.
// ---------------------------------------------------------------------------
__global__ __launch_bounds__(256) void fnet(
    const float* __restrict__ Gpart,
    const float* __restrict__ fw1, const float* __restrict__ fb1,
    const float* __restrict__ fw2, const float* __restrict__ fb2,
    const float* __restrict__ fw3, const float* __restrict__ fb3,
    float* __restrict__ out)
{
  const int b = blockIdx.x, t = threadIdx.x;
  __shared__ float s0[256], s1[256], lg[10];
  float g = 0.f;
  for (int j = 0; j < 64; ++j)
    g += Gpart[(size_t)(b * 64 + j) * 256 + t];
  s0[t] = g;
  __syncthreads();
  float acc = fb1[t];
  for (int k = 0; k < 256; ++k) acc += s0[k] * fw1[k * 256 + t];
  s1[t] = fmaxf(acc, 0.f);
  __syncthreads();
  acc = fb2[t];
  for (int k = 0; k < 256; ++k) acc += s1[k] * fw2[k * 256 + t];
  s0[t] = fmaxf(acc, 0.f);
  __syncthreads();
  if (t < 10) {
    float a = fb3[t];
    for (int k = 0; k < 256; ++k) a += s0[k] * fw3[k * 10 + t];
    lg[t] = a;
  }
  __syncthreads();
  if (t == 0) {
    float m = lg[0];
    for (int c = 1; c < 10; ++c) m = fmaxf(m, lg[c]);
    float e[10], sum = 0.f;
    for (int c = 0; c < 10; ++c) { e[c] = expf(lg[c] - m); sum += e[c]; }
    const float inv = 1.f / sum;
    for (int c = 0; c < 10; ++c) out[b * 10 + c] = e[c] * inv;
  }
}

// ---------------------------------------------------------------------------
extern "C" void kernel_launch(void* const* d_in, const int* in_sizes, int n_in,
                              void* d_out, int out_size, void* d_ws, size_t ws_size,
                              hipStream_t stream)
{
  const float* img = (const float*)d_in[0];
  const float* qst = (const float*)d_in[1];
  const float* cw[4] = {(const float*)d_in[2],  (const float*)d_in[6],
                        (const float*)d_in[10], (const float*)d_in[14]};
  const float* cb[4] = {(const float*)d_in[3],  (const float*)d_in[7],
                        (const float*)d_in[11], (const float*)d_in[15]};
  const float* bg[4] = {(const float*)d_in[4],  (const float*)d_in[8],
                        (const float*)d_in[12], (const float*)d_in[16]};
  const float* bb[4] = {(const float*)d_in[5],  (const float*)d_in[9],
                        (const float*)d_in[13], (const float*)d_in[17]};
  const float* gw1 = (const float*)d_in[18];
  const float* gb1 = (const float*)d_in[19];
  const float* gw2 = (const float*)d_in[20];
  const float* gb2 = (const float*)d_in[21];
  const float* gw3 = (const float*)d_in[22];
  const float* gb3 = (const float*)d_in[23];
  const float* gw4 = (const float*)d_in[24];
  const float* gb4 = (const float*)d_in[25];
  const float* fw1 = (const float*)d_in[26];
  const float* fb1 = (const float*)d_in[27];
  const float* fw2 = (const float*)d_in[28];
  const float* fb2 = (const float*)d_in[29];
  const float* fw3 = (const float*)d_in[30];
  const float* fb3 = (const float*)d_in[31];
  float* out = (float*)d_out;

  float* ws    = (float*)d_ws;
  float* x1    = ws;                  // 6291456
  float* x2    = x1 + 6291456;        // 1572864
  float* x3    = x2 + 1572864;        // 393216
  float* x4    = x3 + 393216;         // 98304
  float* Abuf  = x4 + 98304;          // 1048576
  float* Bbuf  = Abuf + 1048576;      // 1048576
  float* Cqb   = Bbuf + 1048576;      // 16384
  float* Gpart = Cqb + 16384;         // 1048576
  float* stats = Gpart + 1048576;     // 192
  unsigned short* wtb = (unsigned short*)(stats + 192);  // 196608 halfs

  wt_convert_frag<<<24, 256, 0, stream>>>(gw2, gw3, gw4, wtb, stats);

  convk<3, 128, 1, false><<<1024, 256, 0, stream>>>(
      img, cw[0], cb[0], nullptr, nullptr, nullptr, x1, stats + 0);
  convk<24, 64, 4, true><<<1024, 256, 0, stream>>>(
      x1, cw[1], cb[1], stats + 0, bg[0], bb[0], x2, stats + 48);
  convk<24, 32, 4, true><<<256, 256, 0, stream>>>(
      x2, cw[2], cb[2], stats + 48, bg[1], bb[1], x3, stats + 96);
  convk<24, 16, 4, true><<<64, 256, 0, stream>>>(
      x3, cw[3], cb[3], stats + 96, bg[2], bb[2], x4, stats + 144);

  build_ab<<<512, 256, 0, stream>>>(x4, stats + 144, bg[3], bb[3], gw1,
                                    gb1, qst, Abuf, Bbuf, Cqb);

  pair_mfma<<<4096, 256, 0, stream>>>(Abuf, Bbuf, Cqb, wtb, gb2, gb3, gb4,
                                      Gpart);
  fnet<<<64, 256, 0, stream>>>(Gpart, fw1, fb1, fw2, fb2, fw3, fb3, out);
}